// Round 4
// baseline (315.487 us; speedup 1.0000x reference)
//
#include <hip/hip_runtime.h>
#include <hip/hip_bf16.h>
#include <stdint.h>

#define NH 12
#define DH 64
#define CC 768
#define NTOK 197
#define PFX 10
#define MKV 207
#define BB 64
#define MROWS (BB * NTOK)   // 12608
#define MPAD (99 * 128)     // 12672 padded rows so global_load_lds never faults
#define KV_PAD 208          // 13 * 16
#define KV_PAD2 224         // 7 * 32

typedef __attribute__((__ext_vector_type__(8))) short bf16x8;
typedef __attribute__((__ext_vector_type__(4))) float f32x4;

__device__ __forceinline__ ushort f2bf(float f) {
    union { float f; uint32_t u; } x; x.f = f;
    uint32_t u = x.u;
    return (ushort)((u + 0x7fffu + ((u >> 16) & 1u)) >> 16);
}

__device__ __forceinline__ void gload_lds16(const void* g, void* l) {
    __builtin_amdgcn_global_load_lds(
        (const __attribute__((address_space(1))) void*)g,
        (__attribute__((address_space(3))) void*)l, 16, 0, 0);
}

// ---------------- convert fp32 -> bf16 (vectorized) ----------------
__global__ void cvt_bf16(const float* __restrict__ src, ushort* __restrict__ dst, int n4) {
    int i = blockIdx.x * 256 + threadIdx.x;
    if (i >= n4) return;
    float4 v = reinterpret_cast<const float4*>(src)[i];
    ushort4 o = make_ushort4(f2bf(v.x), f2bf(v.y), f2bf(v.z), f2bf(v.w));
    reinterpret_cast<ushort4*>(dst)[i] = o;
}

// ---------------- prompt prefix scatter ----------------
// prompt [B,2,P,H,D] fp32 -> kbuf[b,h,p,d] bf16 ; vt[b,h,d,p] bf16
__global__ void prompt_scatter(const float* __restrict__ prompt,
                               ushort* __restrict__ kbuf, ushort* __restrict__ vt) {
    int i = blockIdx.x * 256 + threadIdx.x;
    if (i >= BB * 2 * PFX * NH * DH) return;
    int d = i & 63;
    int h = (i >> 6) % NH;
    int p = (i / (64 * NH)) % PFX;
    int s = (i / (64 * NH * PFX)) & 1;
    int b = i / (64 * NH * PFX * 2);
    ushort val = f2bf(prompt[i]);
    int bh = b * NH + h;
    if (s == 0) kbuf[(bh * KV_PAD + p) * DH + d] = val;
    else        vt[(bh * DH + d) * KV_PAD2 + p] = val;
}

// ---------------- GEMM core: 2-phase double-buffered (T3-min recipe) ----------------
// C[M,N] = A[M,K] @ B[N,K]^T, bf16 row-major both, 128x128 tile, BK=32,
// 4 waves, global_load_lds width-16 staging, 2 LDS buffers: STAGE(next)
// issued BEFORE compute(cur) so the vmcnt(0) drain at the barrier lands
// after ~32 MFMA of overlap. Buffer choice is compile-time (loop unroll x2).

#define GEMM_PRE(A_, B_, KDIM)                                                       \
    __shared__ __align__(16) ushort Alds0[128 * 32];                                 \
    __shared__ __align__(16) ushort Blds0[128 * 32];                                 \
    __shared__ __align__(16) ushort Alds1[128 * 32];                                 \
    __shared__ __align__(16) ushort Blds1[128 * 32];                                 \
    const int tid  = threadIdx.x;                                                    \
    const int lane = tid & 63;                                                       \
    const int wave = tid >> 6;                                                       \
    const int wm = wave >> 1, wn = wave & 1;                                         \
    const int g = lane >> 4, lr = lane & 15;                                         \
    const int row0 = blockIdx.x * 128;                                               \
    const int col0 = blockIdx.y * 128;                                               \
    const int srow = lane >> 2;                                                      \
    const int scol = (lane & 3) * 8;                                                 \
    const ushort* gA0 = &(A_)[(size_t)(row0 + wave * 16 + srow) * (KDIM) + scol];    \
    const ushort* gA1 = gA0 + (size_t)64 * (KDIM);                                   \
    const ushort* gB0 = &(B_)[(size_t)(col0 + wave * 16 + srow) * (KDIM) + scol];    \
    const ushort* gB1 = gB0 + (size_t)64 * (KDIM);                                   \
    f32x4 acc[4][4] = {};

#define GEMM_STAGE(AB, BB_, KOFF)                                                    \
    gload_lds16(gA0 + (KOFF), &(AB)[(wave * 16) * 32]);                              \
    gload_lds16(gA1 + (KOFF), &(AB)[(64 + wave * 16) * 32]);                         \
    gload_lds16(gB0 + (KOFF), &(BB_)[(wave * 16) * 32]);                             \
    gload_lds16(gB1 + (KOFF), &(BB_)[(64 + wave * 16) * 32]);

#define GEMM_COMPUTE(AB, BB_)                                                        \
    {                                                                                \
        bf16x8 af[4], bfr[4];                                                        \
        _Pragma("unroll")                                                            \
        for (int i = 0; i < 4; ++i)                                                  \
            af[i] = *reinterpret_cast<const bf16x8*>(&(AB)[(wm * 64 + i * 16 + lr) * 32 + g * 8]); \
        _Pragma("unroll")                                                            \
        for (int i = 0; i < 4; ++i)                                                  \
            bfr[i] = *reinterpret_cast<const bf16x8*>(&(BB_)[(wn * 64 + i * 16 + lr) * 32 + g * 8]); \
        _Pragma("unroll")                                                            \
        for (int mi = 0; mi < 4; ++mi)                                               \
            _Pragma("unroll")                                                        \
            for (int ni = 0; ni < 4; ++ni)                                           \
                acc[mi][ni] = __builtin_amdgcn_mfma_f32_16x16x32_bf16(af[mi], bfr[ni], acc[mi][ni], 0, 0, 0); \
    }

// KDIM must be a multiple of 64 (768 = 12 double-steps).
#define GEMM_MAIN(A_, B_, KDIM)                                                      \
    GEMM_PRE(A_, B_, KDIM)                                                           \
    GEMM_STAGE(Alds0, Blds0, 0)                                                      \
    __syncthreads();                                                                 \
    for (int k0 = 0; k0 < (KDIM); k0 += 64) {                                        \
        GEMM_STAGE(Alds1, Blds1, k0 + 32)                                            \
        GEMM_COMPUTE(Alds0, Blds0)                                                   \
        __syncthreads();                                                             \
        if (k0 + 64 < (KDIM)) { GEMM_STAGE(Alds0, Blds0, k0 + 64) }                  \
        GEMM_COMPUTE(Alds1, Blds1)                                                   \
        __syncthreads();                                                             \
    }

// GEMM1: X[12608,768] @ qkv_w[2304,768]^T -> scatter q/k/vt (bf16)
__global__ __launch_bounds__(256) void gemm_qkv(const ushort* __restrict__ A,
                                                const ushort* __restrict__ Bw,
                                                ushort* __restrict__ qbuf,
                                                ushort* __restrict__ kbuf,
                                                ushort* __restrict__ vt) {
    GEMM_MAIN(A, Bw, CC)
    #pragma unroll
    for (int ni = 0; ni < 4; ++ni) {
        int f = col0 + wn * 64 + ni * 16 + lr;     // 0..2303
        int s   = f / CC;
        int rem = f - s * CC;
        int h = rem >> 6, d = rem & 63;
        #pragma unroll
        for (int mi = 0; mi < 4; ++mi) {
            #pragma unroll
            for (int rr = 0; rr < 4; ++rr) {
                int r = row0 + wm * 64 + mi * 16 + g * 4 + rr;
                if (r >= MROWS) continue;
                int b = r / NTOK;
                int n = r - b * NTOK;
                ushort val = f2bf(acc[mi][ni][rr]);
                int bh = b * NH + h;
                if (s == 0)      qbuf[(bh * KV_PAD + n) * DH + d] = val;
                else if (s == 1) kbuf[(bh * KV_PAD + n + PFX) * DH + d] = val;
                else             vt[(bh * DH + d) * KV_PAD2 + n + PFX] = val;
            }
        }
    }
}

// GEMM2: aout[12608,768] @ proj_w[768,768]^T + bias -> out fp32
__global__ __launch_bounds__(256) void gemm_proj(const ushort* __restrict__ A,
                                                 const ushort* __restrict__ Bw,
                                                 const float* __restrict__ bias,
                                                 float* __restrict__ out) {
    GEMM_MAIN(A, Bw, CC)
    #pragma unroll
    for (int ni = 0; ni < 4; ++ni) {
        int o = col0 + wn * 64 + ni * 16 + lr;
        float bs = bias[o];
        #pragma unroll
        for (int mi = 0; mi < 4; ++mi) {
            #pragma unroll
            for (int rr = 0; rr < 4; ++rr) {
                int r = row0 + wm * 64 + mi * 16 + g * 4 + rr;
                if (r >= MROWS) continue;
                out[(size_t)r * CC + o] = acc[mi][ni][rr] + bs;
            }
        }
    }
}

// ---------------- attention ----------------
// 1 wave per (q-tile of 16 rows, b*h). Swapped QK^T: S^T = mfma(K, Q).
// Lane (g,lr): holds S^T[kv = t*16 + g*4 + rr][q = qt*16 + lr].
__global__ __launch_bounds__(64) void attn(const ushort* __restrict__ qbuf,
                                           const ushort* __restrict__ kbuf,
                                           const ushort* __restrict__ vt,
                                           ushort* __restrict__ aout) {
    __shared__ __align__(16) ushort Plds[16][232];
    const int lane = threadIdx.x;
    const int g = lane >> 4, lr = lane & 15;
    const int qt = blockIdx.x;           // 0..12
    const int bh = blockIdx.y;           // 0..767
    const int b = bh / NH;
    const int h = bh - b * NH;
    const ushort* Q  = qbuf + (size_t)bh * KV_PAD * DH;
    const ushort* Kb = kbuf + (size_t)bh * KV_PAD * DH;
    const ushort* V  = vt   + (size_t)bh * DH * KV_PAD2;

    bf16x8 qf[2];
    #pragma unroll
    for (int kc = 0; kc < 2; ++kc)
        qf[kc] = *reinterpret_cast<const bf16x8*>(&Q[(qt * 16 + lr) * DH + kc * 32 + g * 8]);

    f32x4 s[13];
    #pragma unroll
    for (int t = 0; t < 13; ++t) {
        f32x4 a = {};
        #pragma unroll
        for (int kc = 0; kc < 2; ++kc) {
            bf16x8 kf = *reinterpret_cast<const bf16x8*>(&Kb[(t * 16 + lr) * DH + kc * 32 + g * 8]);
            a = __builtin_amdgcn_mfma_f32_16x16x32_bf16(kf, qf[kc], a, 0, 0, 0);
        }
        s[t] = a;
    }

    // mask pad kv rows, row-max
    float m = -1e30f;
    #pragma unroll
    for (int t = 0; t < 13; ++t) {
        #pragma unroll
        for (int rr = 0; rr < 4; ++rr) {
            int kv = t * 16 + g * 4 + rr;
            float v = (kv < MKV) ? s[t][rr] : -1e30f;
            s[t][rr] = v;
            m = fmaxf(m, v);
        }
    }
    m = fmaxf(m, __shfl_xor(m, 16));
    m = fmaxf(m, __shfl_xor(m, 32));

    const float cs = 0.125f * 1.4426950408889634f;  // scale * log2(e)
    float sum = 0.f;
    #pragma unroll
    for (int t = 0; t < 13; ++t) {
        #pragma unroll
        for (int rr = 0; rr < 4; ++rr) {
            float p = exp2f((s[t][rr] - m) * cs);
            s[t][rr] = p;
            sum += p;
        }
    }
    sum += __shfl_xor(sum, 16);
    sum += __shfl_xor(sum, 32);
    float inv = 1.0f / sum;

    // zero P pad (kv 208..223)
    {
        int row = lane >> 2;
        int col = 208 + (lane & 3) * 4;
        *reinterpret_cast<ushort4*>(&Plds[row][col]) = make_ushort4(0, 0, 0, 0);
    }
    #pragma unroll
    for (int t = 0; t < 13; ++t) {
        #pragma unroll
        for (int rr = 0; rr < 4; ++rr)
            Plds[lr][t * 16 + g * 4 + rr] = f2bf(s[t][rr] * inv);
    }
    __syncthreads();

    // PV: out^T = mfma(Vt, P)  -> lane holds out[d = dt*16 + g*4 + rr][q = qt*16 + lr]
    const int q = qt * 16 + lr;
    #pragma unroll
    for (int dt = 0; dt < 4; ++dt) {
        f32x4 o = {};
        #pragma unroll
        for (int kc = 0; kc < 7; ++kc) {
            bf16x8 vf = *reinterpret_cast<const bf16x8*>(&V[(dt * 16 + lr) * KV_PAD2 + kc * 32 + g * 8]);
            bf16x8 pf = *reinterpret_cast<const bf16x8*>(&Plds[lr][kc * 32 + g * 8]);
            o = __builtin_amdgcn_mfma_f32_16x16x32_bf16(vf, pf, o, 0, 0, 0);
        }
        if (q < NTOK) {
            ushort4 st = make_ushort4(f2bf(o[0]), f2bf(o[1]), f2bf(o[2]), f2bf(o[3]));
            int r = b * NTOK + q;
            *reinterpret_cast<ushort4*>(&aout[(size_t)r * CC + h * 64 + dt * 16 + g * 4]) = st;
        }
    }
}

// ---------------- launch ----------------
extern "C" void kernel_launch(void* const* d_in, const int* in_sizes, int n_in,
                              void* d_out, int out_size, void* d_ws, size_t ws_size,
                              hipStream_t stream) {
    const float* x      = (const float*)d_in[0];
    const float* prompt = (const float*)d_in[1];
    const float* qkv_w  = (const float*)d_in[2];
    const float* proj_w = (const float*)d_in[3];
    const float* proj_b = (const float*)d_in[4];
    float* out = (float*)d_out;

    char* ws = (char*)d_ws;
    ushort* Xb = (ushort*)(ws + 0);          // MPAD*768*2       = 19,464,192
    ushort* Wq = (ushort*)(ws + 19464192);   // 2304*768*2       =  3,538,944
    ushort* Wp = (ushort*)(ws + 23003136);   // 768*768*2        =  1,179,648
    ushort* qb = (ushort*)(ws + 24182784);   // 768*208*64*2     = 20,447,232
    ushort* kb = (ushort*)(ws + 44630016);   // 768*208*64*2     = 20,447,232
    ushort* vt = (ushort*)(ws + 65077248);   // 768*64*224*2     = 22,020,096
    ushort* ao = (ushort*)(ws + 87097344);   // MPAD*768*2       = 19,464,192
    // total 106,561,536 bytes

    cvt_bf16<<<dim3((MROWS * CC / 4 + 255) / 256), 256, 0, stream>>>(x, Xb, MROWS * CC / 4);
    cvt_bf16<<<dim3((3 * CC * CC / 4 + 255) / 256), 256, 0, stream>>>(qkv_w, Wq, 3 * CC * CC / 4);
    cvt_bf16<<<dim3((CC * CC / 4 + 255) / 256), 256, 0, stream>>>(proj_w, Wp, CC * CC / 4);
    prompt_scatter<<<dim3((BB * 2 * PFX * NH * DH + 255) / 256), 256, 0, stream>>>(prompt, kb, vt);

    gemm_qkv<<<dim3(99, 18), 256, 0, stream>>>(Xb, Wq, qb, kb, vt);
    attn<<<dim3(13, BB * NH), 64, 0, stream>>>(qb, kb, vt, ao);
    gemm_proj<<<dim3(99, 6), 256, 0, stream>>>(ao, Wp, proj_b, out);
}

// Round 6
// 286.238 us; speedup vs baseline: 1.1022x; 1.1022x over previous
//
#include <hip/hip_runtime.h>
#include <hip/hip_bf16.h>
#include <stdint.h>

#define NH 12
#define DH 64
#define CC 768
#define NTOK 197
#define PFX 10
#define MKV 207
#define BB 64
#define MROWS (BB * NTOK)   // 12608
#define MPAD (99 * 128)     // 12672 padded rows so global_load_lds never faults
#define KV_PAD 208          // 13 * 16
#define KV_PAD2 224         // 7 * 32

typedef __attribute__((__ext_vector_type__(8))) short bf16x8;
typedef __attribute__((__ext_vector_type__(4))) float f32x4;

__device__ __forceinline__ ushort f2bf(float f) {
    union { float f; uint32_t u; } x; x.f = f;
    uint32_t u = x.u;
    return (ushort)((u + 0x7fffu + ((u >> 16) & 1u)) >> 16);
}

__device__ __forceinline__ void gload_lds16(const void* g, void* l) {
    __builtin_amdgcn_global_load_lds(
        (const __attribute__((address_space(1))) void*)g,
        (__attribute__((address_space(3))) void*)l, 16, 0, 0);
}

// Bijective chunked XCD swizzle (m204): blocks with the same (orig % 8) —
// i.e. the same XCD under round-robin dispatch — get CONSECUTIVE logical
// tile ids, so each XCD's L2 sees a contiguous, reused working set.
__device__ __forceinline__ int xcd_chunked(int orig, int nwg) {
    int q = nwg >> 3, r = nwg & 7;
    int xcd = orig & 7, rem = orig >> 3;
    return (xcd < r ? xcd * (q + 1) : r * (q + 1) + (xcd - r) * q) + rem;
}

// ---------------- convert fp32 -> bf16 (vectorized) ----------------
__global__ void cvt_bf16(const float* __restrict__ src, ushort* __restrict__ dst, int n4) {
    int i = blockIdx.x * 256 + threadIdx.x;
    if (i >= n4) return;
    float4 v = reinterpret_cast<const float4*>(src)[i];
    ushort4 o = make_ushort4(f2bf(v.x), f2bf(v.y), f2bf(v.z), f2bf(v.w));
    reinterpret_cast<ushort4*>(dst)[i] = o;
}

// ---------------- prompt prefix scatter ----------------
// prompt [B,2,P,H,D] fp32 -> kbuf[b,h,p,d] bf16 ; vt[b,h,d,p] bf16
__global__ void prompt_scatter(const float* __restrict__ prompt,
                               ushort* __restrict__ kbuf, ushort* __restrict__ vt) {
    int i = blockIdx.x * 256 + threadIdx.x;
    if (i >= BB * 2 * PFX * NH * DH) return;
    int d = i & 63;
    int h = (i >> 6) % NH;
    int p = (i / (64 * NH)) % PFX;
    int s = (i / (64 * NH * PFX)) & 1;
    int b = i / (64 * NH * PFX * 2);
    ushort val = f2bf(prompt[i]);
    int bh = b * NH + h;
    if (s == 0) kbuf[(bh * KV_PAD + p) * DH + d] = val;
    else        vt[(bh * DH + d) * KV_PAD2 + p] = val;
}

// ---------------- GEMM core: 2-phase double-buffered + XCD-chunked tiles ----
// C[M,N] = A[M,K] @ B[N,K]^T, bf16 row-major both, 128x128 tile, BK=32,
// 4 waves, global_load_lds width-16 staging, 2 LDS buffers. Linear grid;
// logical tile = xcd_chunked(blockIdx.x); N-tile fastest within a chunk so
// each XCD reuses one A-panel across all N-tiles and keeps full B resident.

#define GEMM_PRE(A_, B_, KDIM, NTILES)                                               \
    __shared__ __align__(16) ushort Alds0[128 * 32];                                 \
    __shared__ __align__(16) ushort Blds0[128 * 32];                                 \
    __shared__ __align__(16) ushort Alds1[128 * 32];                                 \
    __shared__ __align__(16) ushort Blds1[128 * 32];                                 \
    const int tid  = threadIdx.x;                                                    \
    const int lane = tid & 63;                                                       \
    const int wave = tid >> 6;                                                       \
    const int wm = wave >> 1, wn = wave & 1;                                         \
    const int g = lane >> 4, lr = lane & 15;                                         \
    const int wgid = xcd_chunked(blockIdx.x, gridDim.x);                             \
    const int row0 = (wgid / (NTILES)) * 128;                                        \
    const int col0 = (wgid % (NTILES)) * 128;                                        \
    const int srow = lane >> 2;                                                      \
    const int scol = (lane & 3) * 8;                                                 \
    const ushort* gA0 = &(A_)[(size_t)(row0 + wave * 16 + srow) * (KDIM) + scol];    \
    const ushort* gA1 = gA0 + (size_t)64 * (KDIM);                                   \
    const ushort* gB0 = &(B_)[(size_t)(col0 + wave * 16 + srow) * (KDIM) + scol];    \
    const ushort* gB1 = gB0 + (size_t)64 * (KDIM);                                   \
    f32x4 acc[4][4] = {};

#define GEMM_STAGE(AB, BB_, KOFF)                                                    \
    gload_lds16(gA0 + (KOFF), &(AB)[(wave * 16) * 32]);                              \
    gload_lds16(gA1 + (KOFF), &(AB)[(64 + wave * 16) * 32]);                         \
    gload_lds16(gB0 + (KOFF), &(BB_)[(wave * 16) * 32]);                             \
    gload_lds16(gB1 + (KOFF), &(BB_)[(64 + wave * 16) * 32]);

#define GEMM_COMPUTE(AB, BB_)                                                        \
    {                                                                                \
        bf16x8 af[4], bfr[4];                                                        \
        _Pragma("unroll")                                                            \
        for (int i = 0; i < 4; ++i)                                                  \
            af[i] = *reinterpret_cast<const bf16x8*>(&(AB)[(wm * 64 + i * 16 + lr) * 32 + g * 8]); \
        _Pragma("unroll")                                                            \
        for (int i = 0; i < 4; ++i)                                                  \
            bfr[i] = *reinterpret_cast<const bf16x8*>(&(BB_)[(wn * 64 + i * 16 + lr) * 32 + g * 8]); \
        _Pragma("unroll")                                                            \
        for (int mi = 0; mi < 4; ++mi)                                               \
            _Pragma("unroll")                                                        \
            for (int ni = 0; ni < 4; ++ni)                                           \
                acc[mi][ni] = __builtin_amdgcn_mfma_f32_16x16x32_bf16(af[mi], bfr[ni], acc[mi][ni], 0, 0, 0); \
    }

// KDIM must be a multiple of 64 (768 = 12 double-steps).
#define GEMM_MAIN(A_, B_, KDIM, NTILES)                                              \
    GEMM_PRE(A_, B_, KDIM, NTILES)                                                   \
    GEMM_STAGE(Alds0, Blds0, 0)                                                      \
    __syncthreads();                                                                 \
    for (int k0 = 0; k0 < (KDIM); k0 += 64) {                                        \
        GEMM_STAGE(Alds1, Blds1, k0 + 32)                                            \
        GEMM_COMPUTE(Alds0, Blds0)                                                   \
        __syncthreads();                                                             \
        if (k0 + 64 < (KDIM)) { GEMM_STAGE(Alds0, Blds0, k0 + 64) }                  \
        GEMM_COMPUTE(Alds1, Blds1)                                                   \
        __syncthreads();                                                             \
    }

// GEMM1: X[12608,768] @ qkv_w[2304,768]^T -> scatter q/k/vt (bf16)
__global__ __launch_bounds__(256) void gemm_qkv(const ushort* __restrict__ A,
                                                const ushort* __restrict__ Bw,
                                                ushort* __restrict__ qbuf,
                                                ushort* __restrict__ kbuf,
                                                ushort* __restrict__ vt) {
    GEMM_MAIN(A, Bw, CC, 18)
    #pragma unroll
    for (int ni = 0; ni < 4; ++ni) {
        int f = col0 + wn * 64 + ni * 16 + lr;     // 0..2303
        int s   = f / CC;
        int rem = f - s * CC;
        int h = rem >> 6, d = rem & 63;
        #pragma unroll
        for (int mi = 0; mi < 4; ++mi) {
            #pragma unroll
            for (int rr = 0; rr < 4; ++rr) {
                int r = row0 + wm * 64 + mi * 16 + g * 4 + rr;
                if (r >= MROWS) continue;
                int b = r / NTOK;
                int n = r - b * NTOK;
                ushort val = f2bf(acc[mi][ni][rr]);
                int bh = b * NH + h;
                if (s == 0)      qbuf[(bh * KV_PAD + n) * DH + d] = val;
                else if (s == 1) kbuf[(bh * KV_PAD + n + PFX) * DH + d] = val;
                else             vt[(bh * DH + d) * KV_PAD2 + n + PFX] = val;
            }
        }
    }
}

// GEMM2: aout[12608,768] @ proj_w[768,768]^T + bias -> out fp32
__global__ __launch_bounds__(256) void gemm_proj(const ushort* __restrict__ A,
                                                 const ushort* __restrict__ Bw,
                                                 const float* __restrict__ bias,
                                                 float* __restrict__ out) {
    GEMM_MAIN(A, Bw, CC, 6)
    #pragma unroll
    for (int ni = 0; ni < 4; ++ni) {
        int o = col0 + wn * 64 + ni * 16 + lr;
        float bs = bias[o];
        #pragma unroll
        for (int mi = 0; mi < 4; ++mi) {
            #pragma unroll
            for (int rr = 0; rr < 4; ++rr) {
                int r = row0 + wm * 64 + mi * 16 + g * 4 + rr;
                if (r >= MROWS) continue;
                out[(size_t)r * CC + o] = acc[mi][ni][rr] + bs;
            }
        }
    }
}

// ---------------- attention ----------------
// 1 wave per (q-tile of 16 rows, b*h). Swapped QK^T: S^T = mfma(K, Q).
// Lane (g,lr): holds S^T[kv = t*16 + g*4 + rr][q = qt*16 + lr].
// Linear grid + XCD chunking (bh-major): one bh's 13 blocks stay on one XCD
// so K/V (52 KB) is L2-resident for 12 of 13 reads.
__global__ __launch_bounds__(64) void attn(const ushort* __restrict__ qbuf,
                                           const ushort* __restrict__ kbuf,
                                           const ushort* __restrict__ vt,
                                           ushort* __restrict__ aout) {
    __shared__ __align__(16) ushort Plds[16][232];
    const int lane = threadIdx.x;
    const int g = lane >> 4, lr = lane & 15;
    const int wgid = xcd_chunked(blockIdx.x, gridDim.x);
    const int bh = wgid / 13;            // 0..767
    const int qt = wgid % 13;            // 0..12
    const int b = bh / NH;
    const int h = bh - b * NH;
    const ushort* Q  = qbuf + (size_t)bh * KV_PAD * DH;
    const ushort* Kb = kbuf + (size_t)bh * KV_PAD * DH;
    const ushort* V  = vt   + (size_t)bh * DH * KV_PAD2;

    bf16x8 qf[2];
    #pragma unroll
    for (int kc = 0; kc < 2; ++kc)
        qf[kc] = *reinterpret_cast<const bf16x8*>(&Q[(qt * 16 + lr) * DH + kc * 32 + g * 8]);

    f32x4 s[13];
    __builtin_amdgcn_s_setprio(1);
    #pragma unroll
    for (int t = 0; t < 13; ++t) {
        f32x4 a = {};
        #pragma unroll
        for (int kc = 0; kc < 2; ++kc) {
            bf16x8 kf = *reinterpret_cast<const bf16x8*>(&Kb[(t * 16 + lr) * DH + kc * 32 + g * 8]);
            a = __builtin_amdgcn_mfma_f32_16x16x32_bf16(kf, qf[kc], a, 0, 0, 0);
        }
        s[t] = a;
    }
    __builtin_amdgcn_s_setprio(0);

    // mask pad kv rows, row-max
    float m = -1e30f;
    #pragma unroll
    for (int t = 0; t < 13; ++t) {
        #pragma unroll
        for (int rr = 0; rr < 4; ++rr) {
            int kv = t * 16 + g * 4 + rr;
            float v = (kv < MKV) ? s[t][rr] : -1e30f;
            s[t][rr] = v;
            m = fmaxf(m, v);
        }
    }
    m = fmaxf(m, __shfl_xor(m, 16));
    m = fmaxf(m, __shfl_xor(m, 32));

    const float cs = 0.125f * 1.4426950408889634f;  // scale * log2(e)
    float sum = 0.f;
    #pragma unroll
    for (int t = 0; t < 13; ++t) {
        #pragma unroll
        for (int rr = 0; rr < 4; ++rr) {
            float p = exp2f((s[t][rr] - m) * cs);
            s[t][rr] = p;
            sum += p;
        }
    }
    sum += __shfl_xor(sum, 16);
    sum += __shfl_xor(sum, 32);
    float inv = 1.0f / sum;

    // zero P pad (kv 208..223)
    {
        int row = lane >> 2;
        int col = 208 + (lane & 3) * 4;
        *reinterpret_cast<ushort4*>(&Plds[row][col]) = make_ushort4(0, 0, 0, 0);
    }
    #pragma unroll
    for (int t = 0; t < 13; ++t) {
        #pragma unroll
        for (int rr = 0; rr < 4; ++rr)
            Plds[lr][t * 16 + g * 4 + rr] = f2bf(s[t][rr] * inv);
    }
    __syncthreads();

    // PV: out^T = mfma(Vt, P)  -> lane holds out[d = dt*16 + g*4 + rr][q = qt*16 + lr]
    const int q = qt * 16 + lr;
    #pragma unroll
    for (int dt = 0; dt < 4; ++dt) {
        f32x4 o = {};
        __builtin_amdgcn_s_setprio(1);
        #pragma unroll
        for (int kc = 0; kc < 7; ++kc) {
            bf16x8 vf = *reinterpret_cast<const bf16x8*>(&V[(dt * 16 + lr) * KV_PAD2 + kc * 32 + g * 8]);
            bf16x8 pf = *reinterpret_cast<const bf16x8*>(&Plds[lr][kc * 32 + g * 8]);
            o = __builtin_amdgcn_mfma_f32_16x16x32_bf16(vf, pf, o, 0, 0, 0);
        }
        __builtin_amdgcn_s_setprio(0);
        if (q < NTOK) {
            ushort4 st = make_ushort4(f2bf(o[0]), f2bf(o[1]), f2bf(o[2]), f2bf(o[3]));
            int r = b * NTOK + q;
            *reinterpret_cast<ushort4*>(&aout[(size_t)r * CC + h * 64 + dt * 16 + g * 4]) = st;
        }
    }
}

// ---------------- launch ----------------
extern "C" void kernel_launch(void* const* d_in, const int* in_sizes, int n_in,
                              void* d_out, int out_size, void* d_ws, size_t ws_size,
                              hipStream_t stream) {
    const float* x      = (const float*)d_in[0];
    const float* prompt = (const float*)d_in[1];
    const float* qkv_w  = (const float*)d_in[2];
    const float* proj_w = (const float*)d_in[3];
    const float* proj_b = (const float*)d_in[4];
    float* out = (float*)d_out;

    char* ws = (char*)d_ws;
    ushort* Xb = (ushort*)(ws + 0);          // MPAD*768*2       = 19,464,192
    ushort* Wq = (ushort*)(ws + 19464192);   // 2304*768*2       =  3,538,944
    ushort* Wp = (ushort*)(ws + 23003136);   // 768*768*2        =  1,179,648
    ushort* qb = (ushort*)(ws + 24182784);   // 768*208*64*2     = 20,447,232
    ushort* kb = (ushort*)(ws + 44630016);   // 768*208*64*2     = 20,447,232
    ushort* vt = (ushort*)(ws + 65077248);   // 768*64*224*2     = 22,020,096
    ushort* ao = (ushort*)(ws + 87097344);   // MPAD*768*2       = 19,464,192
    // total 106,561,536 bytes

    cvt_bf16<<<dim3((MROWS * CC / 4 + 255) / 256), 256, 0, stream>>>(x, Xb, MROWS * CC / 4);
    cvt_bf16<<<dim3((3 * CC * CC / 4 + 255) / 256), 256, 0, stream>>>(qkv_w, Wq, 3 * CC * CC / 4);
    cvt_bf16<<<dim3((CC * CC / 4 + 255) / 256), 256, 0, stream>>>(proj_w, Wp, CC * CC / 4);
    prompt_scatter<<<dim3((BB * 2 * PFX * NH * DH + 255) / 256), 256, 0, stream>>>(prompt, kb, vt);

    gemm_qkv<<<dim3(99 * 18), 256, 0, stream>>>(Xb, Wq, qb, kb, vt);
    attn<<<dim3(13 * BB * NH), 64, 0, stream>>>(qb, kb, vt, ao);
    gemm_proj<<<dim3(99 * 6), 256, 0, stream>>>(ao, Wp, proj_b, out);
}